// Round 1
// baseline (738.085 us; speedup 1.0000x reference)
//
#include <hip/hip_runtime.h>
#include <hip/hip_bf16.h>

// Problem constants
static constexpr int B    = 8;
static constexpr int Cin  = 64;
static constexpr int Cout = 64;
static constexpr int H    = 96;
static constexpr int W    = 96;
static constexpr int HW   = H * W;               // 9216
static constexpr int NPIX = B * H * W;           // 73728
static constexpr int NOFF = 18;                  // 2*K*K
static constexpr float EPS = 1e-5f;

// ---------------------------------------------------------------------------
// Kernel 0: repack weights
//   wdefT[k*4096 + c*64 + co] = w_def[(co*64 + c)*9 + k]
//   woffT[(c*9 + t)*18 + o]   = w_off[(o*64 + c)*9 + t]
// ---------------------------------------------------------------------------
__global__ void repack_weights(const float* __restrict__ w_off,
                               const float* __restrict__ w_def,
                               float* __restrict__ woffT,
                               float* __restrict__ wdefT) {
    int stride = gridDim.x * blockDim.x;
    int t0 = blockIdx.x * blockDim.x + threadIdx.x;
    for (int i = t0; i < 64 * 64 * 9; i += stride) {
        int k  = i / 4096;
        int c  = (i / 64) % 64;
        int co = i % 64;
        wdefT[i] = w_def[(co * 64 + c) * 9 + k];
    }
    for (int i = t0; i < 576 * 18; i += stride) {
        int o   = i % 18;
        int ct  = i / 18;
        int c   = ct / 9;
        int tap = ct % 9;
        woffT[i] = w_off[(o * 64 + c) * 9 + tap];
    }
}

// ---------------------------------------------------------------------------
// Kernel 1: offset conv — one thread per output pixel, 18 accumulators
// offset[b, o, h, w] = sum_{c,i,j} x[b,c,h+i-1,w+j-1] * w_off[o,c,i,j] + b_off[o]
// ---------------------------------------------------------------------------
__global__ __launch_bounds__(256) void offset_conv(const float* __restrict__ x,
                                                   const float* __restrict__ woffT,
                                                   const float* __restrict__ b_off,
                                                   float* __restrict__ offset) {
    int t = blockIdx.x * blockDim.x + threadIdx.x;
    if (t >= NPIX) return;
    int b   = t / HW;
    int rem = t % HW;
    int h   = rem / W;
    int w   = rem % W;

    float acc[NOFF];
#pragma unroll
    for (int o = 0; o < NOFF; ++o) acc[o] = b_off[o];

    const float* xb = x + (size_t)b * Cin * HW;
    for (int c = 0; c < Cin; ++c) {
        const float* xc = xb + c * HW;
#pragma unroll
        for (int di = 0; di < 3; ++di) {
            int yy = h + di - 1;
            bool vy = (yy >= 0) && (yy < H);
#pragma unroll
            for (int dj = 0; dj < 3; ++dj) {
                int xx = w + dj - 1;
                float xv = (vy && xx >= 0 && xx < W) ? xc[yy * W + xx] : 0.f;
                const float* wp = woffT + (c * 9 + di * 3 + dj) * NOFF;
#pragma unroll
                for (int o = 0; o < NOFF; ++o) acc[o] += xv * wp[o];
            }
        }
    }
#pragma unroll
    for (int o = 0; o < NOFF; ++o)
        offset[((size_t)b * NOFF + o) * HW + rem] = acc[o];
}

// ---------------------------------------------------------------------------
// Kernel 2: deformable conv — one thread per output pixel, 64 Cout accumulators.
// Also produces per-block partial sums/sumsq per channel for BN.
// y written to d_out (pre-BN).
// ---------------------------------------------------------------------------
__global__ __launch_bounds__(256) void deform_conv(const float* __restrict__ x,
                                                   const float* __restrict__ offset,
                                                   const float* __restrict__ wdefT,
                                                   const float* __restrict__ b_def,
                                                   float* __restrict__ y,
                                                   float* __restrict__ partial) {
    int t   = blockIdx.x * blockDim.x + threadIdx.x;   // grid is exact: 288*256 = 73728
    int b   = t / HW;
    int rem = t % HW;
    int h   = rem / W;
    int w   = rem % W;

    float acc[Cout];
#pragma unroll
    for (int co = 0; co < Cout; ++co) acc[co] = 0.f;

    const float* xb   = x + (size_t)b * Cin * HW;
    const float* offb = offset + (size_t)b * NOFF * HW + rem;

    for (int k = 0; k < 9; ++k) {
        float dy = offb[(2 * k) * HW];
        float dx = offb[(2 * k + 1) * HW];
        float py = dy + (float)(k / 3) + (float)(h - 1);
        float px = dx + (float)(k % 3) + (float)(w - 1);
        float y0f = floorf(py);
        float x0f = floorf(px);
        float wy1 = py - y0f;
        float wx1 = px - x0f;
        float wy0 = 1.f - wy1;
        float wx0 = 1.f - wx1;
        int iy0 = (int)y0f, ix0 = (int)x0f;
        int iy1 = iy0 + 1,  ix1 = ix0 + 1;
        bool vy0 = (iy0 >= 0) && (iy0 < H);
        bool vy1 = (iy1 >= 0) && (iy1 < H);
        bool vx0 = (ix0 >= 0) && (ix0 < W);
        bool vx1 = (ix1 >= 0) && (ix1 < W);
        float w00 = (vy0 && vx0) ? wy0 * wx0 : 0.f;
        float w01 = (vy0 && vx1) ? wy0 * wx1 : 0.f;
        float w10 = (vy1 && vx0) ? wy1 * wx0 : 0.f;
        float w11 = (vy1 && vx1) ? wy1 * wx1 : 0.f;
        int cy0 = min(max(iy0, 0), H - 1);
        int cy1 = min(max(iy1, 0), H - 1);
        int cx0 = min(max(ix0, 0), W - 1);
        int cx1 = min(max(ix1, 0), W - 1);
        int i00 = cy0 * W + cx0;
        int i01 = cy0 * W + cx1;
        int i10 = cy1 * W + cx0;
        int i11 = cy1 * W + cx1;

        const float* wk = wdefT + k * (64 * 64);
        for (int c = 0; c < Cin; ++c) {
            const float* xc = xb + c * HW;
            float v = w00 * xc[i00] + w01 * xc[i01] + w10 * xc[i10] + w11 * xc[i11];
            const float* wp = wk + c * 64;
#pragma unroll
            for (int co = 0; co < Cout; ++co) acc[co] += v * wp[co];
        }
    }

    // add bias, write y
#pragma unroll
    for (int co = 0; co < Cout; ++co) {
        acc[co] += b_def[co];
        y[((size_t)b * Cout + co) * HW + rem] = acc[co];
    }

    // per-block BN partial sums
    __shared__ float s_sum[Cout];
    __shared__ float s_sq[Cout];
    if (threadIdx.x < Cout) {
        s_sum[threadIdx.x] = 0.f;
        s_sq[threadIdx.x]  = 0.f;
    }
    __syncthreads();
#pragma unroll
    for (int co = 0; co < Cout; ++co) {
        atomicAdd(&s_sum[co], acc[co]);
        atomicAdd(&s_sq[co], acc[co] * acc[co]);
    }
    __syncthreads();
    if (threadIdx.x < Cout) {
        partial[(size_t)blockIdx.x * 128 + threadIdx.x]      = s_sum[threadIdx.x];
        partial[(size_t)blockIdx.x * 128 + 64 + threadIdx.x] = s_sq[threadIdx.x];
    }
}

// ---------------------------------------------------------------------------
// Kernel 3: reduce partials -> per-channel scale/shift
// ---------------------------------------------------------------------------
__global__ void bn_stats(const float* __restrict__ partial,
                         const float* __restrict__ gamma,
                         const float* __restrict__ beta,
                         float* __restrict__ stats,
                         int nblocks) {
    int ch = threadIdx.x;
    if (ch >= Cout) return;
    float s = 0.f, q = 0.f;
    for (int i = 0; i < nblocks; ++i) {
        s += partial[(size_t)i * 128 + ch];
        q += partial[(size_t)i * 128 + 64 + ch];
    }
    const float invN = 1.f / (float)NPIX;
    float mean = s * invN;
    float var  = q * invN - mean * mean;
    float v    = var + EPS;
    float inv  = rsqrtf(v);
    inv = inv * (1.5f - 0.5f * v * inv * inv);   // Newton refinement
    float sc = gamma[ch] * inv;
    stats[ch]        = sc;
    stats[64 + ch]   = beta[ch] - mean * sc;
}

// ---------------------------------------------------------------------------
// Kernel 4: in-place scale/shift/ReLU on y (d_out), float4 vectorized
// ---------------------------------------------------------------------------
__global__ __launch_bounds__(256) void bn_apply(float* __restrict__ y,
                                                const float* __restrict__ stats) {
    int t = blockIdx.x * blockDim.x + threadIdx.x;   // exact: 4608*256 float4 slots
    int e = t * 4;                                   // element index
    int ch = (e / HW) % Cout;
    float sc = stats[ch];
    float sh = stats[64 + ch];
    float4 v = *reinterpret_cast<float4*>(y + e);
    v.x = fmaxf(v.x * sc + sh, 0.f);
    v.y = fmaxf(v.y * sc + sh, 0.f);
    v.z = fmaxf(v.z * sc + sh, 0.f);
    v.w = fmaxf(v.w * sc + sh, 0.f);
    *reinterpret_cast<float4*>(y + e) = v;
}

// ---------------------------------------------------------------------------
extern "C" void kernel_launch(void* const* d_in, const int* in_sizes, int n_in,
                              void* d_out, int out_size, void* d_ws, size_t ws_size,
                              hipStream_t stream) {
    const float* x     = (const float*)d_in[0];
    const float* w_off = (const float*)d_in[1];
    const float* b_off = (const float*)d_in[2];
    const float* w_def = (const float*)d_in[3];
    const float* b_def = (const float*)d_in[4];
    const float* gamma = (const float*)d_in[5];
    const float* beta  = (const float*)d_in[6];
    float* out = (float*)d_out;
    float* ws  = (float*)d_ws;

    // ws layout (floats)
    float* offset  = ws;                       // B*18*HW = 1,327,104
    float* woffT   = offset + (size_t)B * NOFF * HW;
    float* wdefT   = woffT + 576 * 18;         // 10,368
    float* partial = wdefT + 64 * 64 * 9;      // 36,864
    float* stats   = partial + 288 * 128;      // 36,864 -> +128

    constexpr int nblocks = NPIX / 256;        // 288

    repack_weights<<<64, 256, 0, stream>>>(w_off, w_def, woffT, wdefT);
    offset_conv<<<nblocks, 256, 0, stream>>>(x, woffT, b_off, offset);
    deform_conv<<<nblocks, 256, 0, stream>>>(x, offset, wdefT, b_def, out, partial);
    bn_stats<<<1, 64, 0, stream>>>(partial, gamma, beta, stats, nblocks);
    bn_apply<<<(NPIX * Cout / 4) / 256, 256, 0, stream>>>(out, stats);
}

// Round 2
// 362.143 us; speedup vs baseline: 2.0381x; 2.0381x over previous
//
#include <hip/hip_runtime.h>
#include <hip/hip_bf16.h>
#include <stdint.h>

static constexpr int NBATCH = 8;
static constexpr int Cin  = 64;
static constexpr int Cout = 64;
static constexpr int H = 96, W = 96;
static constexpr int HW   = H * W;          // 9216
static constexpr int NPIX = NBATCH * HW;    // 73728
static constexpr int NOFF = 18;
static constexpr int KDIM = 576;            // 9 taps * 64 Cin
static constexpr float EPS = 1e-5f;

typedef short bf16x8 __attribute__((ext_vector_type(8)));
typedef float f32x4  __attribute__((ext_vector_type(4)));

__device__ inline void gld_lds16(const void* g, void* l) {
    __builtin_amdgcn_global_load_lds(
        (const __attribute__((address_space(1))) void*)g,
        (__attribute__((address_space(3))) void*)l, 16, 0, 0);
}

__device__ inline uint16_t f2bf(float f) {
    __hip_bfloat16 h = __float2bfloat16(f);
    return *reinterpret_cast<uint16_t*>(&h);
}

// ---------------------------------------------------------------------------
// Kernel 0: repack weights.
//   woffT[(c*9+tap)*18 + o] = w_off[(o*64+c)*9 + tap]        (fp32)
//   Bpack fragment layout for 16x16x32 MFMA B-operand, k = tap*64 + c:
//   Bpack[((s*4+g)*64 + n)*8 + e] = bf16(w_def[(n*64+c)*9+tap]), k = (s*4+g)*8+e
// ---------------------------------------------------------------------------
__global__ void repack(const float* __restrict__ w_off,
                       const float* __restrict__ w_def,
                       float* __restrict__ woffT,
                       uint16_t* __restrict__ Bpack) {
    int t0 = blockIdx.x * blockDim.x + threadIdx.x;
    int stride = gridDim.x * blockDim.x;
    for (int i = t0; i < KDIM * NOFF; i += stride) {
        int o = i % NOFF;
        int ct = i / NOFF;
        int c = ct / 9, tap = ct % 9;
        woffT[i] = w_off[(o * Cin + c) * 9 + tap];
    }
    for (int i = t0; i < KDIM * Cout; i += stride) {
        int e = i & 7;
        int n = (i >> 3) & 63;
        int sg = i >> 9;                  // s*4+g
        int k = sg * 8 + e;               // global K index
        int tap = k >> 6, c = k & 63;
        Bpack[i] = f2bf(w_def[(n * Cin + c) * 9 + tap]);
    }
}

// ---------------------------------------------------------------------------
// Kernel 1: offset conv — 4 threads per pixel (split over Cin), LDS reduce.
// Grid: NPIX/64 blocks x 256 threads. Block covers 64 consecutive pixels.
// ---------------------------------------------------------------------------
__global__ __launch_bounds__(256) void offset_conv(const float* __restrict__ x,
                                                   const float* __restrict__ woffT,
                                                   const float* __restrict__ b_off,
                                                   float* __restrict__ offset) {
    __shared__ float s_acc[64 * NOFF];
    int tid = threadIdx.x;
    for (int i = tid; i < 64 * NOFF; i += 256) s_acc[i] = 0.f;
    __syncthreads();

    int p  = tid & 63;
    int cq = tid >> 6;
    int pix = blockIdx.x * 64 + p;
    int b = pix / HW, rem = pix % HW;
    int h = rem / W, w = rem % W;

    float acc[NOFF];
#pragma unroll
    for (int o = 0; o < NOFF; ++o) acc[o] = 0.f;

    const float* xb = x + (size_t)b * Cin * HW;
    for (int ci = 0; ci < 16; ++ci) {
        int c = cq * 16 + ci;
        const float* xc = xb + c * HW;
#pragma unroll
        for (int di = 0; di < 3; ++di) {
            int yy = h + di - 1;
            bool vy = (yy >= 0) && (yy < H);
#pragma unroll
            for (int dj = 0; dj < 3; ++dj) {
                int xx = w + dj - 1;
                float xv = (vy && xx >= 0 && xx < W) ? xc[yy * W + xx] : 0.f;
                const float* wp = woffT + (c * 9 + di * 3 + dj) * NOFF;
#pragma unroll
                for (int o = 0; o < NOFF; ++o) acc[o] += xv * wp[o];
            }
        }
    }
#pragma unroll
    for (int o = 0; o < NOFF; ++o) atomicAdd(&s_acc[p * NOFF + o], acc[o]);
    __syncthreads();

    int b_blk = (blockIdx.x * 64) / HW;
    int rem0  = (blockIdx.x * 64) % HW;
    for (int i = tid; i < 64 * NOFF; i += 256) {
        int o = i >> 6, pp = i & 63;
        offset[((size_t)b_blk * NOFF + o) * HW + rem0 + pp] = s_acc[pp * NOFF + o] + b_off[o];
    }
}

// ---------------------------------------------------------------------------
// Kernel 2: bilinear sampling -> im2col A (bf16), A[pl][tap*64 + c].
// One thread per (pixel, tap); chunk-local pixel pl in [0, P).
// ---------------------------------------------------------------------------
__global__ __launch_bounds__(256) void sample_kernel(const float* __restrict__ x,
                                                     const float* __restrict__ offset,
                                                     uint16_t* __restrict__ A,
                                                     int b0, int P) {
    int t = blockIdx.x * 256 + threadIdx.x;
    int tap = t / P;
    int pl  = t - tap * P;
    int b   = b0 + pl / HW;
    int rem = pl % HW;
    int h = rem / W, w = rem % W;

    const float* offb = offset + ((size_t)b * NOFF + 2 * tap) * HW + rem;
    float dy = offb[0];
    float dx = offb[HW];
    float py = dy + (float)(tap / 3) + (float)(h - 1);
    float px = dx + (float)(tap % 3) + (float)(w - 1);
    float y0f = floorf(py), x0f = floorf(px);
    float wy1 = py - y0f, wx1 = px - x0f;
    float wy0 = 1.f - wy1, wx0 = 1.f - wx1;
    int iy0 = (int)y0f, ix0 = (int)x0f;
    int iy1 = iy0 + 1,  ix1 = ix0 + 1;
    bool vy0 = (iy0 >= 0) && (iy0 < H), vy1 = (iy1 >= 0) && (iy1 < H);
    bool vx0 = (ix0 >= 0) && (ix0 < W), vx1 = (ix1 >= 0) && (ix1 < W);
    float w00 = (vy0 && vx0) ? wy0 * wx0 : 0.f;
    float w01 = (vy0 && vx1) ? wy0 * wx1 : 0.f;
    float w10 = (vy1 && vx0) ? wy1 * wx0 : 0.f;
    float w11 = (vy1 && vx1) ? wy1 * wx1 : 0.f;
    int cy0 = min(max(iy0, 0), H - 1), cy1 = min(max(iy1, 0), H - 1);
    int cx0 = min(max(ix0, 0), W - 1), cx1 = min(max(ix1, 0), W - 1);
    int i00 = cy0 * W + cx0, i01 = cy0 * W + cx1;
    int i10 = cy1 * W + cx0, i11 = cy1 * W + cx1;

    const float* xb = x + (size_t)b * Cin * HW;
    uint16_t* outp = A + (size_t)pl * KDIM + tap * 64;

    for (int c0 = 0; c0 < 64; c0 += 8) {
        bf16x8 v;
#pragma unroll
        for (int e = 0; e < 8; ++e) {
            const float* xc = xb + (c0 + e) * HW;
            float s = w00 * xc[i00] + w01 * xc[i01] + w10 * xc[i10] + w11 * xc[i11];
            v[e] = (short)f2bf(s);
        }
        *reinterpret_cast<bf16x8*>(outp + c0) = v;
    }
}

// ---------------------------------------------------------------------------
// Kernel 3: MFMA GEMM. BM=64 pixels, N=64, K=576 (18 steps of 32).
// 4 waves: wave w owns pixel rows 16w..16w+15 and all 64 couts (4 N-frags).
// BN partial sums fused in epilogue.
// ---------------------------------------------------------------------------
__global__ __launch_bounds__(256) void deform_gemm(const uint16_t* __restrict__ A,
                                                   const uint16_t* __restrict__ Bpack,
                                                   float* __restrict__ y,
                                                   float* __restrict__ partial,
                                                   int b0, int blkoff) {
    __shared__ uint16_t As[2048];   // [g:4][row:64][8 bf16] = 4KB
    __shared__ uint16_t Bs[2048];   // [g:4][n:64][8 bf16]   = 4KB
    __shared__ float s_red[128];

    int tid  = threadIdx.x;
    int lane = tid & 63;
    int wv   = tid >> 6;
    int l15  = lane & 15;
    int lg   = lane >> 4;
    int m0   = blockIdx.x * 64;     // chunk-local pixel base

    f32x4 acc[4];
#pragma unroll
    for (int j = 0; j < 4; ++j) acc[j] = (f32x4){0.f, 0.f, 0.f, 0.f};

    // staging mapping: chunk index = tid -> (g = tid>>6, row = tid&63)
    const uint16_t* Ag = A + (size_t)(m0 + (tid & 63)) * KDIM + (tid >> 6) * 8;
    uint16_t* As_dst = As + (size_t)(tid & ~63) * 8;   // wave-uniform base
    uint16_t* Bs_dst = Bs + (size_t)(tid & ~63) * 8;

    for (int s = 0; s < 18; ++s) {
        if (s) __syncthreads();                      // LDS reuse guard
        gld_lds16(Ag + s * 32, As_dst);
        gld_lds16(Bpack + (size_t)(s * 256 + tid) * 8, Bs_dst);
        __syncthreads();                             // drains vmcnt before barrier

        bf16x8 a = *reinterpret_cast<const bf16x8*>(&As[lg * 512 + (16 * wv + l15) * 8]);
#pragma unroll
        for (int j = 0; j < 4; ++j) {
            bf16x8 bb = *reinterpret_cast<const bf16x8*>(&Bs[lg * 512 + (j * 16 + l15) * 8]);
            acc[j] = __builtin_amdgcn_mfma_f32_16x16x32_bf16(a, bb, acc[j], 0, 0, 0);
        }
    }

    // epilogue: C/D layout col=lane&15 (cout), row=(lane>>4)*4+reg (pixel)
    int gpix0 = b0 * HW + m0;
    int bb    = gpix0 / HW;
    int rem00 = gpix0 % HW;
#pragma unroll
    for (int j = 0; j < 4; ++j) {
        int cout = j * 16 + l15;
        float* yp = y + ((size_t)bb * Cout + cout) * HW + rem00 + 16 * wv + lg * 4;
        *reinterpret_cast<f32x4*>(yp) = acc[j];
    }

    // BN partials
    if (tid < 128) s_red[tid] = 0.f;
    __syncthreads();
#pragma unroll
    for (int j = 0; j < 4; ++j) {
        float s = acc[j][0] + acc[j][1] + acc[j][2] + acc[j][3];
        float q = acc[j][0]*acc[j][0] + acc[j][1]*acc[j][1] +
                  acc[j][2]*acc[j][2] + acc[j][3]*acc[j][3];
        s += __shfl_xor(s, 16); s += __shfl_xor(s, 32);
        q += __shfl_xor(q, 16); q += __shfl_xor(q, 32);
        if (lg == 0) {
            atomicAdd(&s_red[j * 16 + l15], s);
            atomicAdd(&s_red[64 + j * 16 + l15], q);
        }
    }
    __syncthreads();
    if (tid < 128) partial[(size_t)(blkoff + blockIdx.x) * 128 + tid] = s_red[tid];
}

// ---------------------------------------------------------------------------
// Kernel 4: reduce partials -> per-channel scale/shift
// ---------------------------------------------------------------------------
__global__ void bn_stats(const float* __restrict__ partial,
                         const float* __restrict__ gamma,
                         const float* __restrict__ beta,
                         float* __restrict__ stats) {
    __shared__ float red[512];
    int ch = threadIdx.x & 63, part = threadIdx.x >> 6;
    float s = 0.f, q = 0.f;
    for (int i = part; i < NPIX / 64; i += 4) {
        s += partial[(size_t)i * 128 + ch];
        q += partial[(size_t)i * 128 + 64 + ch];
    }
    red[part * 64 + ch] = s;
    red[256 + part * 64 + ch] = q;
    __syncthreads();
    if (part == 0) {
        s = red[ch] + red[64 + ch] + red[128 + ch] + red[192 + ch];
        q = red[256 + ch] + red[320 + ch] + red[384 + ch] + red[448 + ch];
        float mean = s / (float)NPIX;
        float var  = q / (float)NPIX - mean * mean;
        float v    = var + EPS;
        float inv  = rsqrtf(v);
        inv = inv * (1.5f - 0.5f * v * inv * inv);
        float sc = gamma[ch] * inv;
        stats[ch]      = sc;
        stats[64 + ch] = beta[ch] - mean * sc;
    }
}

// ---------------------------------------------------------------------------
// Kernel 5: in-place scale/shift/ReLU, float4
// ---------------------------------------------------------------------------
__global__ __launch_bounds__(256) void bn_apply(float* __restrict__ y,
                                                const float* __restrict__ stats) {
    int t = blockIdx.x * blockDim.x + threadIdx.x;
    int e = t * 4;
    int ch = (e / HW) % Cout;
    float sc = stats[ch];
    float sh = stats[64 + ch];
    float4 v = *reinterpret_cast<float4*>(y + e);
    v.x = fmaxf(v.x * sc + sh, 0.f);
    v.y = fmaxf(v.y * sc + sh, 0.f);
    v.z = fmaxf(v.z * sc + sh, 0.f);
    v.w = fmaxf(v.w * sc + sh, 0.f);
    *reinterpret_cast<float4*>(y + e) = v;
}

// ---------------------------------------------------------------------------
extern "C" void kernel_launch(void* const* d_in, const int* in_sizes, int n_in,
                              void* d_out, int out_size, void* d_ws, size_t ws_size,
                              hipStream_t stream) {
    const float* x     = (const float*)d_in[0];
    const float* w_off = (const float*)d_in[1];
    const float* b_off = (const float*)d_in[2];
    const float* w_def = (const float*)d_in[3];
    // d_in[4] = b_def: constant shift, cancels exactly in BatchNorm — omitted
    const float* gamma = (const float*)d_in[5];
    const float* beta  = (const float*)d_in[6];
    float* out = (float*)d_out;
    char*  ws  = (char*)d_ws;

    // ws layout (bytes)
    float*    offset  = (float*)ws;                        // 5,308,416
    float*    woffT   = (float*)(ws + 5308416);            //    41,472
    float*    partial = (float*)(ws + 5349888);            //   589,824
    float*    stats   = (float*)(ws + 5939712);            //       512 (pad 1024)
    uint16_t* Bpack   = (uint16_t*)(ws + 5940736);         //    73,728
    uint16_t* Abuf    = (uint16_t*)(ws + 6014464);         // up to 84,934,656

    const size_t fixed = 6014464;
    const size_t per_batch = (size_t)HW * KDIM * 2;        // 10,616,832
    size_t avail = (ws_size > fixed) ? ws_size - fixed : 0;
    int nb = (int)(avail / per_batch);
    if (nb < 1) nb = 1;
    if (nb > NBATCH) nb = NBATCH;

    repack<<<64, 256, 0, stream>>>(w_off, w_def, woffT, Bpack);
    offset_conv<<<NPIX / 64, 256, 0, stream>>>(x, woffT, b_off, offset);

    for (int b0 = 0; b0 < NBATCH; b0 += nb) {
        int nbc = (nb < NBATCH - b0) ? nb : (NBATCH - b0);
        int P = nbc * HW;
        sample_kernel<<<(P * 9) / 256, 256, 0, stream>>>(x, offset, Abuf, b0, P);
        deform_gemm<<<P / 64, 256, 0, stream>>>(Abuf, Bpack, out, partial, b0, b0 * (HW / 64));
    }

    bn_stats<<<1, 256, 0, stream>>>(partial, gamma, beta, stats);
    bn_apply<<<(NPIX * Cout / 4) / 256, 256, 0, stream>>>(out, stats);
}

// Round 3
// 178.517 us; speedup vs baseline: 4.1345x; 2.0286x over previous
//
#include <hip/hip_runtime.h>
#include <hip/hip_bf16.h>
#include <stdint.h>

static constexpr int NBATCH = 8;
static constexpr int Cin  = 64;
static constexpr int Cout = 64;
static constexpr int H = 96, W = 96;
static constexpr int HW   = H * W;          // 9216
static constexpr int NPIX = NBATCH * HW;    // 73728
static constexpr int NBLK = NPIX / 64;      // 1152
static constexpr float EPS = 1e-5f;

typedef short  bf16x8 __attribute__((ext_vector_type(8)));
typedef float  f32x4  __attribute__((ext_vector_type(4)));

__device__ inline uint16_t f2bf(float f) {
    __hip_bfloat16 h = __float2bfloat16(f);
    return *reinterpret_cast<uint16_t*>(&h);
}
__device__ inline float bf2f(uint16_t u) {
    union { uint32_t i; float f; } z;
    z.i = ((uint32_t)u) << 16;
    return z.f;
}

// ---------------------------------------------------------------------------
// Kernel 0: pack weights into MFMA B-fragment order, bf16.
//   element layout [sg:72][n][e:8], value = w[n][c][tap] with k = sg*8+e,
//   tap = k>>6, c = k&63.   woffPack: n in [0,32) (>=18 zero). wdefPack: n in [0,64).
// ---------------------------------------------------------------------------
__global__ void repack(const float* __restrict__ w_off,
                       const float* __restrict__ w_def,
                       uint16_t* __restrict__ woffPack,
                       uint16_t* __restrict__ wdefPack) {
    int t0 = blockIdx.x * blockDim.x + threadIdx.x;
    int stride = gridDim.x * blockDim.x;
    for (int i = t0; i < 72 * 32 * 8; i += stride) {
        int e = i & 7;
        int n = (i >> 3) & 31;
        int sg = i >> 8;
        int k = sg * 8 + e;
        int tap = k >> 6, c = k & 63;
        woffPack[i] = (n < 18) ? f2bf(w_off[(n * Cin + c) * 9 + tap]) : (uint16_t)0;
    }
    for (int i = t0; i < 72 * 64 * 8; i += stride) {
        int e = i & 7;
        int n = (i >> 3) & 63;
        int sg = i >> 9;
        int k = sg * 8 + e;
        int tap = k >> 6, c = k & 63;
        wdefPack[i] = f2bf(w_def[(n * Cin + c) * 9 + tap]);
    }
}

// ---------------------------------------------------------------------------
// Kernel 1: transpose x (NCHW f32) -> xT (N,HW,C) bf16
// ---------------------------------------------------------------------------
__global__ __launch_bounds__(256) void transpose_x(const float* __restrict__ x,
                                                   uint16_t* __restrict__ xT) {
    int t = blockIdx.x * 256 + threadIdx.x;      // global pixel, exact grid
    int b = t / HW, rem = t % HW;
    const float* xb = x + (size_t)(b * Cin) * HW + rem;
    uint16_t* o = xT + (size_t)t * 64;
#pragma unroll
    for (int cg = 0; cg < 8; ++cg) {
        bf16x8 v;
#pragma unroll
        for (int e = 0; e < 8; ++e) v[e] = (short)f2bf(xb[(cg * 8 + e) * HW]);
        *reinterpret_cast<bf16x8*>(o + cg * 8) = v;
    }
}

// ---------------------------------------------------------------------------
// Kernel 2: fully fused deformable block (per 64-pixel tile):
//  P1: plain 3x3 im2col tile -> LDS As [sg:72][row:64][e:8] bf16
//  P2: MFMA x woffPack -> offsets (LDS offs[64][18])
//  P3: bilinear sampling -> overwrite As with deformed im2col
//  P4: MFMA x wdefPack -> y (+ BN partial sums)
// ---------------------------------------------------------------------------
__global__ __launch_bounds__(256, 2) void fused_deform(
        const uint16_t* __restrict__ xT,
        const uint16_t* __restrict__ woffPack,
        const uint16_t* __restrict__ wdefPack,
        const float* __restrict__ b_off,
        float* __restrict__ y,
        float* __restrict__ partial) {
    __shared__ short As[72 * 64 * 8];     // 73728 B
    __shared__ float offs[64 * 18];       //  4608 B
    __shared__ float s_red[128];          //   512 B

    int tid  = threadIdx.x;
    int lane = tid & 63;
    int wv   = tid >> 6;
    int l15  = lane & 15;
    int lg   = lane >> 4;

    int gpix0 = blockIdx.x * 64;
    int b     = gpix0 / HW;
    int rem0  = gpix0 % HW;
    int row   = lane;                 // this thread's pixel row for item loops
    int rem   = rem0 + row;
    int h     = rem / W, w = rem % W;
    const uint16_t* xTb = xT + (size_t)b * HW * 64;

    // ---- Phase 1: plain im2col ----
#pragma unroll
    for (int k = 0; k < 18; ++k) {
        int gt  = wv + 4 * k;         // 0..71, unique per (wv,k)
        int grp = gt / 9, tap = gt % 9;
        int yy = h + tap / 3 - 1;
        int xx = w + tap % 3 - 1;
        bf16x8 v = (bf16x8){0, 0, 0, 0, 0, 0, 0, 0};
        if (yy >= 0 && yy < H && xx >= 0 && xx < W)
            v = *reinterpret_cast<const bf16x8*>(xTb + (yy * W + xx) * 64 + grp * 8);
        *reinterpret_cast<bf16x8*>(&As[((8 * tap + grp) * 64 + row) * 8]) = v;
    }
    __syncthreads();

    // ---- Phase 2: offset GEMM (N=32, j=0..1) ----
    f32x4 oacc[2];
    oacc[0] = (f32x4){0.f, 0.f, 0.f, 0.f};
    oacc[1] = (f32x4){0.f, 0.f, 0.f, 0.f};
#pragma unroll
    for (int s = 0; s < 18; ++s) {
        bf16x8 a = *reinterpret_cast<const bf16x8*>(
            &As[((s * 4 + lg) * 64 + wv * 16 + l15) * 8]);
#pragma unroll
        for (int j = 0; j < 2; ++j) {
            bf16x8 bb = *reinterpret_cast<const bf16x8*>(
                woffPack + ((s * 4 + lg) * 32 + j * 16 + l15) * 8);
            oacc[j] = __builtin_amdgcn_mfma_f32_16x16x32_bf16(a, bb, oacc[j], 0, 0, 0);
        }
    }
#pragma unroll
    for (int j = 0; j < 2; ++j) {
        int o = j * 16 + l15;
        if (o < 18) {
            float bo = b_off[o];
#pragma unroll
            for (int r = 0; r < 4; ++r)
                offs[(wv * 16 + lg * 4 + r) * 18 + o] = oacc[j][r] + bo;
        }
    }
    __syncthreads();   // As reads done (phase 2), offs visible

    // ---- Phase 3: bilinear sampling -> As ----
    float hm1 = (float)(h - 1), wm1 = (float)(w - 1);
#pragma unroll
    for (int k = 0; k < 18; ++k) {
        int gt  = wv + 4 * k;
        int grp = gt / 9, tap = gt % 9;
        float dy = offs[row * 18 + 2 * tap];
        float dx = offs[row * 18 + 2 * tap + 1];
        float py = dy + (float)(tap / 3) + hm1;
        float px = dx + (float)(tap % 3) + wm1;
        float y0f = floorf(py), x0f = floorf(px);
        float wy1 = py - y0f, wx1 = px - x0f;
        float wy0 = 1.f - wy1, wx0 = 1.f - wx1;
        int iy0 = (int)y0f, ix0 = (int)x0f;
        int iy1 = iy0 + 1,  ix1 = ix0 + 1;
        bool vy0 = (iy0 >= 0) && (iy0 < H), vy1 = (iy1 >= 0) && (iy1 < H);
        bool vx0 = (ix0 >= 0) && (ix0 < W), vx1 = (ix1 >= 0) && (ix1 < W);
        float w00 = (vy0 && vx0) ? wy0 * wx0 : 0.f;
        float w01 = (vy0 && vx1) ? wy0 * wx1 : 0.f;
        float w10 = (vy1 && vx0) ? wy1 * wx0 : 0.f;
        float w11 = (vy1 && vx1) ? wy1 * wx1 : 0.f;
        int cy0 = min(max(iy0, 0), H - 1), cy1 = min(max(iy1, 0), H - 1);
        int cx0 = min(max(ix0, 0), W - 1), cx1 = min(max(ix1, 0), W - 1);
        const uint16_t* base = xTb + grp * 8;
        bf16x8 v00 = *reinterpret_cast<const bf16x8*>(base + (cy0 * W + cx0) * 64);
        bf16x8 v01 = *reinterpret_cast<const bf16x8*>(base + (cy0 * W + cx1) * 64);
        bf16x8 v10 = *reinterpret_cast<const bf16x8*>(base + (cy1 * W + cx0) * 64);
        bf16x8 v11 = *reinterpret_cast<const bf16x8*>(base + (cy1 * W + cx1) * 64);
        bf16x8 outv;
#pragma unroll
        for (int e = 0; e < 8; ++e) {
            float s = w00 * bf2f((uint16_t)v00[e]) + w01 * bf2f((uint16_t)v01[e])
                    + w10 * bf2f((uint16_t)v10[e]) + w11 * bf2f((uint16_t)v11[e]);
            outv[e] = (short)f2bf(s);
        }
        *reinterpret_cast<bf16x8*>(&As[((8 * tap + grp) * 64 + row) * 8]) = outv;
    }
    __syncthreads();

    // ---- Phase 4: deform GEMM (N=64, j=0..3) ----
    f32x4 acc[4];
#pragma unroll
    for (int j = 0; j < 4; ++j) acc[j] = (f32x4){0.f, 0.f, 0.f, 0.f};
#pragma unroll
    for (int s = 0; s < 18; ++s) {
        bf16x8 a = *reinterpret_cast<const bf16x8*>(
            &As[((s * 4 + lg) * 64 + wv * 16 + l15) * 8]);
#pragma unroll
        for (int j = 0; j < 4; ++j) {
            bf16x8 bb = *reinterpret_cast<const bf16x8*>(
                wdefPack + ((s * 4 + lg) * 64 + j * 16 + l15) * 8);
            acc[j] = __builtin_amdgcn_mfma_f32_16x16x32_bf16(a, bb, acc[j], 0, 0, 0);
        }
    }

    // epilogue: C/D layout col=lane&15 (cout), row=(lane>>4)*4+reg (pixel)
#pragma unroll
    for (int j = 0; j < 4; ++j) {
        int cout = j * 16 + l15;
        float* yp = y + ((size_t)b * Cout + cout) * HW + rem0 + 16 * wv + lg * 4;
        *reinterpret_cast<f32x4*>(yp) = acc[j];
    }

    // BN partials
    if (tid < 128) s_red[tid] = 0.f;
    __syncthreads();
#pragma unroll
    for (int j = 0; j < 4; ++j) {
        float s = acc[j][0] + acc[j][1] + acc[j][2] + acc[j][3];
        float q = acc[j][0]*acc[j][0] + acc[j][1]*acc[j][1] +
                  acc[j][2]*acc[j][2] + acc[j][3]*acc[j][3];
        s += __shfl_xor(s, 16); s += __shfl_xor(s, 32);
        q += __shfl_xor(q, 16); q += __shfl_xor(q, 32);
        if (lg == 0) {
            atomicAdd(&s_red[j * 16 + l15], s);
            atomicAdd(&s_red[64 + j * 16 + l15], q);
        }
    }
    __syncthreads();
    if (tid < 128) partial[(size_t)blockIdx.x * 128 + tid] = s_red[tid];
}

// ---------------------------------------------------------------------------
// Kernel 3: reduce partials -> per-channel scale/shift
// ---------------------------------------------------------------------------
__global__ void bn_stats(const float* __restrict__ partial,
                         const float* __restrict__ gamma,
                         const float* __restrict__ beta,
                         float* __restrict__ stats) {
    __shared__ float red[512];
    int ch = threadIdx.x & 63, part = threadIdx.x >> 6;
    float s = 0.f, q = 0.f;
    for (int i = part; i < NBLK; i += 4) {
        s += partial[(size_t)i * 128 + ch];
        q += partial[(size_t)i * 128 + 64 + ch];
    }
    red[part * 64 + ch] = s;
    red[256 + part * 64 + ch] = q;
    __syncthreads();
    if (part == 0) {
        s = red[ch] + red[64 + ch] + red[128 + ch] + red[192 + ch];
        q = red[256 + ch] + red[320 + ch] + red[384 + ch] + red[448 + ch];
        float mean = s / (float)NPIX;
        float var  = q / (float)NPIX - mean * mean;
        float v    = var + EPS;
        float inv  = rsqrtf(v);
        inv = inv * (1.5f - 0.5f * v * inv * inv);
        float sc = gamma[ch] * inv;
        stats[ch]      = sc;
        stats[64 + ch] = beta[ch] - mean * sc;
    }
}

// ---------------------------------------------------------------------------
// Kernel 4: in-place scale/shift/ReLU, float4
// ---------------------------------------------------------------------------
__global__ __launch_bounds__(256) void bn_apply(float* __restrict__ y,
                                                const float* __restrict__ stats) {
    int t = blockIdx.x * blockDim.x + threadIdx.x;
    int e = t * 4;
    int ch = (e / HW) % Cout;
    float sc = stats[ch];
    float sh = stats[64 + ch];
    float4 v = *reinterpret_cast<float4*>(y + e);
    v.x = fmaxf(v.x * sc + sh, 0.f);
    v.y = fmaxf(v.y * sc + sh, 0.f);
    v.z = fmaxf(v.z * sc + sh, 0.f);
    v.w = fmaxf(v.w * sc + sh, 0.f);
    *reinterpret_cast<float4*>(y + e) = v;
}

// ---------------------------------------------------------------------------
extern "C" void kernel_launch(void* const* d_in, const int* in_sizes, int n_in,
                              void* d_out, int out_size, void* d_ws, size_t ws_size,
                              hipStream_t stream) {
    const float* x     = (const float*)d_in[0];
    const float* w_off = (const float*)d_in[1];
    const float* b_off = (const float*)d_in[2];
    const float* w_def = (const float*)d_in[3];
    // d_in[4] = b_def: constant shift, cancels exactly in BatchNorm — omitted
    const float* gamma = (const float*)d_in[5];
    const float* beta  = (const float*)d_in[6];
    float* out = (float*)d_out;
    char*  ws  = (char*)d_ws;

    // ws layout (bytes)
    uint16_t* xT       = (uint16_t*)ws;                    // 9,437,184
    uint16_t* woffPack = (uint16_t*)(ws + 9437184);        //    36,864
    uint16_t* wdefPack = (uint16_t*)(ws + 9474048);        //    73,728
    float*    partial  = (float*)(ws + 9547776);           //   589,824
    float*    stats    = (float*)(ws + 10137600);          //       512

    repack<<<64, 256, 0, stream>>>(w_off, w_def, woffPack, wdefPack);
    transpose_x<<<NPIX / 256, 256, 0, stream>>>(x, xT);
    fused_deform<<<NBLK, 256, 0, stream>>>(xT, woffPack, wdefPack, b_off,
                                           out, partial);
    bn_stats<<<1, 256, 0, stream>>>(partial, gamma, beta, stats);
    bn_apply<<<(NPIX * Cout / 4) / 256, 256, 0, stream>>>(out, stats);
}

// Round 4
// 172.977 us; speedup vs baseline: 4.2670x; 1.0320x over previous
//
#include <hip/hip_runtime.h>
#include <hip/hip_bf16.h>
#include <stdint.h>

static constexpr int NBATCH = 8;
static constexpr int Cin  = 64;
static constexpr int Cout = 64;
static constexpr int H = 96, W = 96;
static constexpr int HW   = H * W;          // 9216
static constexpr int NPIX = NBATCH * HW;    // 73728
static constexpr int NBLK = NPIX / 64;      // 1152
static constexpr int BLK_PER_BATCH = HW / 64; // 144
static constexpr float EPS = 1e-5f;

typedef short  bf16x8 __attribute__((ext_vector_type(8)));
typedef float  f32x4  __attribute__((ext_vector_type(4)));

__device__ inline uint16_t f2bf(float f) {
    __hip_bfloat16 h = __float2bfloat16(f);
    return *reinterpret_cast<uint16_t*>(&h);
}
__device__ inline float bf2f(uint16_t u) {
    union { uint32_t i; float f; } z;
    z.i = ((uint32_t)u) << 16;
    return z.f;
}

// ---------------------------------------------------------------------------
// Kernel 0: pack weights into MFMA B-fragment order, bf16.
//   layout [sg:72][n][e:8], value = w[n][c][tap], k = sg*8+e, tap=k>>6, c=k&63
// ---------------------------------------------------------------------------
__global__ void repack(const float* __restrict__ w_off,
                       const float* __restrict__ w_def,
                       uint16_t* __restrict__ woffPack,
                       uint16_t* __restrict__ wdefPack) {
    int t0 = blockIdx.x * blockDim.x + threadIdx.x;
    int stride = gridDim.x * blockDim.x;
    for (int i = t0; i < 72 * 32 * 8; i += stride) {
        int e = i & 7;
        int n = (i >> 3) & 31;
        int sg = i >> 8;
        int k = sg * 8 + e;
        int tap = k >> 6, c = k & 63;
        woffPack[i] = (n < 18) ? f2bf(w_off[(n * Cin + c) * 9 + tap]) : (uint16_t)0;
    }
    for (int i = t0; i < 72 * 64 * 8; i += stride) {
        int e = i & 7;
        int n = (i >> 3) & 63;
        int sg = i >> 9;
        int k = sg * 8 + e;
        int tap = k >> 6, c = k & 63;
        wdefPack[i] = f2bf(w_def[(n * Cin + c) * 9 + tap]);
    }
}

// ---------------------------------------------------------------------------
// Kernel 1: transpose x (NCHW f32) -> xT (N,HW,C) bf16. 2 threads/pixel.
// ---------------------------------------------------------------------------
__global__ __launch_bounds__(256) void transpose_x(const float* __restrict__ x,
                                                   uint16_t* __restrict__ xT) {
    int t = blockIdx.x * 256 + threadIdx.x;      // exact grid: NPIX*2 threads
    int pix  = t >> 1;
    int half = t & 1;
    int b = pix / HW, rem = pix % HW;
    const float* xb = x + (size_t)(b * Cin) * HW + rem + (size_t)(half * 32) * HW;
    uint16_t* o = xT + (size_t)pix * 64 + half * 32;
#pragma unroll
    for (int cg = 0; cg < 4; ++cg) {
        bf16x8 v;
#pragma unroll
        for (int e = 0; e < 8; ++e) v[e] = (short)f2bf(xb[(cg * 8 + e) * HW]);
        *reinterpret_cast<bf16x8*>(o + cg * 8) = v;
    }
}

// ---------------------------------------------------------------------------
// Kernel 2: fully fused deformable block, 512 threads (8 waves) / 64-pixel tile.
//  P1: plain 3x3 im2col tile -> LDS As [sg:72][row:64][e:8] bf16
//  P2: MFMA x woffPack -> offsets (LDS offs[64][18])
//  P3: bilinear sampling -> overwrite As with deformed im2col
//  P4: MFMA x wdefPack -> y (+ BN partial sums)
// Wave wv: sampling sg = wv*9..wv*9+8; MFMA rows (wv&3)*16.., N-frag (wv>>2).
// ---------------------------------------------------------------------------
__global__ __launch_bounds__(512, 4) void fused_deform(
        const uint16_t* __restrict__ xT,
        const uint16_t* __restrict__ woffPack,
        const uint16_t* __restrict__ wdefPack,
        const float* __restrict__ b_off,
        float* __restrict__ y,
        float* __restrict__ partial) {
    __shared__ short As[72 * 64 * 8];     // 73728 B
    __shared__ float offs[64 * 18];       //  4608 B
    __shared__ float s_red[128];          //   512 B

    int tid  = threadIdx.x;
    int lane = tid & 63;
    int wv   = tid >> 6;                  // 0..7
    int l15  = lane & 15;
    int lg   = lane >> 4;
    int wq   = wv & 3;                    // row quarter for MFMA
    int wj   = wv >> 2;                   // N-split for MFMA

    // XCD-aware swizzle: batch b -> XCD b (144 tiles per batch, 8 XCDs)
    int wgid  = (blockIdx.x & 7) * BLK_PER_BATCH + (blockIdx.x >> 3);
    int gpix0 = wgid * 64;
    int b     = gpix0 / HW;
    int rem0  = gpix0 % HW;
    int row   = lane;
    int rem   = rem0 + row;
    int h     = rem / W, w = rem % W;
    const uint16_t* xTb = xT + (size_t)b * HW * 64;

    // ---- Phase 1: plain im2col (each wave: 9 sg groups) ----
#pragma unroll
    for (int k = 0; k < 9; ++k) {
        int sg  = wv * 9 + k;             // 0..71
        int tap = sg >> 3, grp = sg & 7;
        int yy = h + tap / 3 - 1;
        int xx = w + tap % 3 - 1;
        bf16x8 v = (bf16x8){0, 0, 0, 0, 0, 0, 0, 0};
        if (yy >= 0 && yy < H && xx >= 0 && xx < W)
            v = *reinterpret_cast<const bf16x8*>(xTb + (yy * W + xx) * 64 + grp * 8);
        *reinterpret_cast<bf16x8*>(&As[(sg * 64 + row) * 8]) = v;
    }
    __syncthreads();

    // ---- Phase 2: offset GEMM (N=32; wave -> rows wq*16, N-frag wj) ----
    f32x4 oacc = (f32x4){0.f, 0.f, 0.f, 0.f};
#pragma unroll
    for (int s = 0; s < 18; ++s) {
        bf16x8 a = *reinterpret_cast<const bf16x8*>(
            &As[((s * 4 + lg) * 64 + wq * 16 + l15) * 8]);
        bf16x8 bb = *reinterpret_cast<const bf16x8*>(
            woffPack + ((s * 4 + lg) * 32 + wj * 16 + l15) * 8);
        oacc = __builtin_amdgcn_mfma_f32_16x16x32_bf16(a, bb, oacc, 0, 0, 0);
    }
    {
        int o = wj * 16 + l15;
        if (o < 18) {
            float bo = b_off[o];
#pragma unroll
            for (int r = 0; r < 4; ++r)
                offs[(wq * 16 + lg * 4 + r) * 18 + o] = oacc[r] + bo;
        }
    }
    __syncthreads();   // As reads done (phase 2), offs visible

    // ---- Phase 3: bilinear sampling -> As ----
    float hm1 = (float)(h - 1), wm1 = (float)(w - 1);
#pragma unroll
    for (int k = 0; k < 9; ++k) {
        int sg  = wv * 9 + k;
        int tap = sg >> 3, grp = sg & 7;
        float dy = offs[row * 18 + 2 * tap];
        float dx = offs[row * 18 + 2 * tap + 1];
        float py = dy + (float)(tap / 3) + hm1;
        float px = dx + (float)(tap % 3) + wm1;
        float y0f = floorf(py), x0f = floorf(px);
        float wy1 = py - y0f, wx1 = px - x0f;
        float wy0 = 1.f - wy1, wx0 = 1.f - wx1;
        int iy0 = (int)y0f, ix0 = (int)x0f;
        int iy1 = iy0 + 1,  ix1 = ix0 + 1;
        bool vy0 = (iy0 >= 0) && (iy0 < H), vy1 = (iy1 >= 0) && (iy1 < H);
        bool vx0 = (ix0 >= 0) && (ix0 < W), vx1 = (ix1 >= 0) && (ix1 < W);
        float w00 = (vy0 && vx0) ? wy0 * wx0 : 0.f;
        float w01 = (vy0 && vx1) ? wy0 * wx1 : 0.f;
        float w10 = (vy1 && vx0) ? wy1 * wx0 : 0.f;
        float w11 = (vy1 && vx1) ? wy1 * wx1 : 0.f;
        int cy0 = min(max(iy0, 0), H - 1), cy1 = min(max(iy1, 0), H - 1);
        int cx0 = min(max(ix0, 0), W - 1), cx1 = min(max(ix1, 0), W - 1);
        const uint16_t* base = xTb + grp * 8;
        bf16x8 v00 = *reinterpret_cast<const bf16x8*>(base + (cy0 * W + cx0) * 64);
        bf16x8 v01 = *reinterpret_cast<const bf16x8*>(base + (cy0 * W + cx1) * 64);
        bf16x8 v10 = *reinterpret_cast<const bf16x8*>(base + (cy1 * W + cx0) * 64);
        bf16x8 v11 = *reinterpret_cast<const bf16x8*>(base + (cy1 * W + cx1) * 64);
        bf16x8 outv;
#pragma unroll
        for (int e = 0; e < 8; ++e) {
            float s = w00 * bf2f((uint16_t)v00[e]) + w01 * bf2f((uint16_t)v01[e])
                    + w10 * bf2f((uint16_t)v10[e]) + w11 * bf2f((uint16_t)v11[e]);
            outv[e] = (short)f2bf(s);
        }
        *reinterpret_cast<bf16x8*>(&As[(sg * 64 + row) * 8]) = outv;
    }
    __syncthreads();

    // ---- Phase 4: deform GEMM (N=64; wave -> rows wq*16, N-frags wj*2+{0,1}) ----
    f32x4 acc[2];
    acc[0] = (f32x4){0.f, 0.f, 0.f, 0.f};
    acc[1] = (f32x4){0.f, 0.f, 0.f, 0.f};
#pragma unroll
    for (int s = 0; s < 18; ++s) {
        bf16x8 a = *reinterpret_cast<const bf16x8*>(
            &As[((s * 4 + lg) * 64 + wq * 16 + l15) * 8]);
#pragma unroll
        for (int jj = 0; jj < 2; ++jj) {
            int j = wj * 2 + jj;
            bf16x8 bb = *reinterpret_cast<const bf16x8*>(
                wdefPack + ((s * 4 + lg) * 64 + j * 16 + l15) * 8);
            acc[jj] = __builtin_amdgcn_mfma_f32_16x16x32_bf16(a, bb, acc[jj], 0, 0, 0);
        }
    }

    // epilogue: C/D layout col=lane&15 (cout), row=(lane>>4)*4+reg (pixel)
#pragma unroll
    for (int jj = 0; jj < 2; ++jj) {
        int cout = (wj * 2 + jj) * 16 + l15;
        float* yp = y + ((size_t)b * Cout + cout) * HW + rem0 + 16 * wq + lg * 4;
        *reinterpret_cast<f32x4*>(yp) = acc[jj];
    }

    // BN partials
    if (tid < 128) s_red[tid] = 0.f;
    __syncthreads();
#pragma unroll
    for (int jj = 0; jj < 2; ++jj) {
        int j = wj * 2 + jj;
        float s = acc[jj][0] + acc[jj][1] + acc[jj][2] + acc[jj][3];
        float q = acc[jj][0]*acc[jj][0] + acc[jj][1]*acc[jj][1] +
                  acc[jj][2]*acc[jj][2] + acc[jj][3]*acc[jj][3];
        s += __shfl_xor(s, 16); s += __shfl_xor(s, 32);
        q += __shfl_xor(q, 16); q += __shfl_xor(q, 32);
        if (lg == 0) {
            atomicAdd(&s_red[j * 16 + l15], s);
            atomicAdd(&s_red[64 + j * 16 + l15], q);
        }
    }
    __syncthreads();
    if (tid < 128) partial[(size_t)wgid * 128 + tid] = s_red[tid];
}

// ---------------------------------------------------------------------------
// Kernel 3: reduce partials -> per-channel scale/shift
// ---------------------------------------------------------------------------
__global__ void bn_stats(const float* __restrict__ partial,
                         const float* __restrict__ gamma,
                         const float* __restrict__ beta,
                         float* __restrict__ stats) {
    __shared__ float red[512];
    int ch = threadIdx.x & 63, part = threadIdx.x >> 6;
    float s = 0.f, q = 0.f;
    for (int i = part; i < NBLK; i += 4) {
        s += partial[(size_t)i * 128 + ch];
        q += partial[(size_t)i * 128 + 64 + ch];
    }
    red[part * 64 + ch] = s;
    red[256 + part * 64 + ch] = q;
    __syncthreads();
    if (part == 0) {
        s = red[ch] + red[64 + ch] + red[128 + ch] + red[192 + ch];
        q = red[256 + ch] + red[320 + ch] + red[384 + ch] + red[448 + ch];
        float mean = s / (float)NPIX;
        float var  = q / (float)NPIX - mean * mean;
        float v    = var + EPS;
        float inv  = rsqrtf(v);
        inv = inv * (1.5f - 0.5f * v * inv * inv);
        float sc = gamma[ch] * inv;
        stats[ch]      = sc;
        stats[64 + ch] = beta[ch] - mean * sc;
    }
}

// ---------------------------------------------------------------------------
// Kernel 4: in-place scale/shift/ReLU, float4
// ---------------------------------------------------------------------------
__global__ __launch_bounds__(256) void bn_apply(float* __restrict__ y,
                                                const float* __restrict__ stats) {
    int t = blockIdx.x * blockDim.x + threadIdx.x;
    int e = t * 4;
    int ch = (e / HW) % Cout;
    float sc = stats[ch];
    float sh = stats[64 + ch];
    float4 v = *reinterpret_cast<float4*>(y + e);
    v.x = fmaxf(v.x * sc + sh, 0.f);
    v.y = fmaxf(v.y * sc + sh, 0.f);
    v.z = fmaxf(v.z * sc + sh, 0.f);
    v.w = fmaxf(v.w * sc + sh, 0.f);
    *reinterpret_cast<float4*>(y + e) = v;
}

// ---------------------------------------------------------------------------
extern "C" void kernel_launch(void* const* d_in, const int* in_sizes, int n_in,
                              void* d_out, int out_size, void* d_ws, size_t ws_size,
                              hipStream_t stream) {
    const float* x     = (const float*)d_in[0];
    const float* w_off = (const float*)d_in[1];
    const float* b_off = (const float*)d_in[2];
    const float* w_def = (const float*)d_in[3];
    // d_in[4] = b_def: constant shift, cancels exactly in BatchNorm — omitted
    const float* gamma = (const float*)d_in[5];
    const float* beta  = (const float*)d_in[6];
    float* out = (float*)d_out;
    char*  ws  = (char*)d_ws;

    // ws layout (bytes)
    uint16_t* xT       = (uint16_t*)ws;                    // 9,437,184
    uint16_t* woffPack = (uint16_t*)(ws + 9437184);        //    36,864
    uint16_t* wdefPack = (uint16_t*)(ws + 9474048);        //    73,728
    float*    partial  = (float*)(ws + 9547776);           //   589,824
    float*    stats    = (float*)(ws + 10137600);          //       512

    repack<<<64, 256, 0, stream>>>(w_off, w_def, woffPack, wdefPack);
    transpose_x<<<NPIX * 2 / 256, 256, 0, stream>>>(x, xT);
    fused_deform<<<NBLK, 512, 0, stream>>>(xT, woffPack, wdefPack, b_off,
                                           out, partial);
    bn_stats<<<1, 256, 0, stream>>>(partial, gamma, beta, stats);
    bn_apply<<<(NPIX * Cout / 4) / 256, 256, 0, stream>>>(out, stats);
}

// Round 5
// 71.046 us; speedup vs baseline: 10.3888x; 2.4347x over previous
//
#include <hip/hip_runtime.h>
#include <hip/hip_bf16.h>
#include <stdint.h>

static constexpr int NBATCH = 8;
static constexpr int Cin  = 64;
static constexpr int Cout = 64;
static constexpr int H = 96, W = 96;
static constexpr int HW   = H * W;          // 9216
static constexpr int NPIX = NBATCH * HW;    // 73728
static constexpr int NBLK = NPIX / 64;      // 1152
static constexpr int BLK_PER_BATCH = HW / 64; // 144
static constexpr float EPS = 1e-5f;

typedef short  bf16x8 __attribute__((ext_vector_type(8)));
typedef float  f32x4  __attribute__((ext_vector_type(4)));

__device__ inline uint16_t f2bf(float f) {
    __hip_bfloat16 h = __float2bfloat16(f);
    return *reinterpret_cast<uint16_t*>(&h);
}
__device__ inline float bf2f(uint16_t u) {
    union { uint32_t i; float f; } z;
    z.i = ((uint32_t)u) << 16;
    return z.f;
}

// ---------------------------------------------------------------------------
// Kernel 0: pack weights into MFMA B-fragment order, bf16.
//   layout [sg:72][n][e:8], value = w[n][c][tap], k = sg*8+e, tap=k>>6, c=k&63
// ---------------------------------------------------------------------------
__global__ void repack(const float* __restrict__ w_off,
                       const float* __restrict__ w_def,
                       uint16_t* __restrict__ woffPack,
                       uint16_t* __restrict__ wdefPack) {
    int t0 = blockIdx.x * blockDim.x + threadIdx.x;
    int stride = gridDim.x * blockDim.x;
    for (int i = t0; i < 72 * 32 * 8; i += stride) {
        int e = i & 7;
        int n = (i >> 3) & 31;
        int sg = i >> 8;
        int k = sg * 8 + e;
        int tap = k >> 6, c = k & 63;
        woffPack[i] = (n < 18) ? f2bf(w_off[(n * Cin + c) * 9 + tap]) : (uint16_t)0;
    }
    for (int i = t0; i < 72 * 64 * 8; i += stride) {
        int e = i & 7;
        int n = (i >> 3) & 63;
        int sg = i >> 9;
        int k = sg * 8 + e;
        int tap = k >> 6, c = k & 63;
        wdefPack[i] = f2bf(w_def[(n * Cin + c) * 9 + tap]);
    }
}

// ---------------------------------------------------------------------------
// Kernel 1: transpose x (NCHW f32) -> xT (N,HW,C) bf16. 2 threads/pixel.
// ---------------------------------------------------------------------------
__global__ __launch_bounds__(256) void transpose_x(const float* __restrict__ x,
                                                   uint16_t* __restrict__ xT) {
    int t = blockIdx.x * 256 + threadIdx.x;      // exact grid: NPIX*2 threads
    int pix  = t >> 1;
    int half = t & 1;
    int b = pix / HW, rem = pix % HW;
    const float* xb = x + (size_t)(b * Cin) * HW + rem + (size_t)(half * 32) * HW;
    uint16_t* o = xT + (size_t)pix * 64 + half * 32;
#pragma unroll
    for (int cg = 0; cg < 4; ++cg) {
        bf16x8 v;
#pragma unroll
        for (int e = 0; e < 8; ++e) v[e] = (short)f2bf(xb[(cg * 8 + e) * HW]);
        *reinterpret_cast<bf16x8*>(o + cg * 8) = v;
    }
}

// ---------------------------------------------------------------------------
// Kernel 2: fused deformable block, 512 threads / 64-pixel tile.
// LDS As layout: [tap:9][pix:64][slot:8][8 bf16], slot = chunk ^ (pix&7).
// Gather phases use pixel-major lanes: 8 lanes/pixel, lane&7 = channel chunk
// -> every 16B lane-load is part of a contiguous 128B pixel vector
// (16 cache lines per wave instr instead of 64).
//  P1: plain 3x3 im2col -> As
//  P2: MFMA x woffPack -> offs[64][18]
//  P3: bilinear sampling -> As (overwrite)
//  P4: MFMA x wdefPack -> y (+ BN partials)
// ---------------------------------------------------------------------------
__global__ __launch_bounds__(512, 4) void fused_deform(
        const uint16_t* __restrict__ xT,
        const uint16_t* __restrict__ woffPack,
        const uint16_t* __restrict__ wdefPack,
        const float* __restrict__ b_off,
        float* __restrict__ y,
        float* __restrict__ partial) {
    __shared__ short As[72 * 64 * 8];     // 73728 B
    __shared__ float offs[64 * 18];       //  4608 B
    __shared__ float s_red[128];          //   512 B

    int tid  = threadIdx.x;
    int lane = tid & 63;
    int wv   = tid >> 6;                  // 0..7
    int l15  = lane & 15;
    int lg   = lane >> 4;
    int wq   = wv & 3;                    // MFMA row quarter
    int wj   = wv >> 2;                   // MFMA N-split

    // XCD-aware swizzle: batch b -> XCD b
    int wgid  = (blockIdx.x & 7) * BLK_PER_BATCH + (blockIdx.x >> 3);
    int gpix0 = wgid * 64;
    int b     = gpix0 / HW;
    int rem0  = gpix0 % HW;
    const uint16_t* xTb = xT + (size_t)b * HW * 64;

    // pixel-major mapping for gather phases
    int pr   = (wv << 3) + (lane >> 3);   // local pixel 0..63
    int e8   = lane & 7;                  // channel chunk (8 ch = 16B)
    int slot = e8 ^ (pr & 7);             // LDS bank swizzle
    int remP = rem0 + pr;
    int hP   = remP / W, wP = remP % W;

    // ---- Phase 1: plain im2col ----
#pragma unroll
    for (int tap = 0; tap < 9; ++tap) {
        int yy = hP + tap / 3 - 1;
        int xx = wP + tap % 3 - 1;
        bf16x8 v = (bf16x8){0, 0, 0, 0, 0, 0, 0, 0};
        if (yy >= 0 && yy < H && xx >= 0 && xx < W)
            v = *reinterpret_cast<const bf16x8*>(xTb + (yy * W + xx) * 64 + e8 * 8);
        *reinterpret_cast<bf16x8*>(&As[((tap * 64 + pr) * 8 + slot) * 8]) = v;
    }
    __syncthreads();

    // ---- Phase 2: offset GEMM (N=32; rows wq*16.., N-frag wj) ----
    f32x4 oacc = (f32x4){0.f, 0.f, 0.f, 0.f};
#pragma unroll
    for (int s = 0; s < 18; ++s) {
        int sg = s * 4 + lg;
        bf16x8 a = *reinterpret_cast<const bf16x8*>(
            &As[(((sg >> 3) * 64 + wq * 16 + l15) * 8 + ((sg & 7) ^ (l15 & 7))) * 8]);
        bf16x8 bb = *reinterpret_cast<const bf16x8*>(
            woffPack + (sg * 32 + wj * 16 + l15) * 8);
        oacc = __builtin_amdgcn_mfma_f32_16x16x32_bf16(a, bb, oacc, 0, 0, 0);
    }
    {
        int o = wj * 16 + l15;
        if (o < 18) {
            float bo = b_off[o];
#pragma unroll
            for (int r = 0; r < 4; ++r)
                offs[(wq * 16 + lg * 4 + r) * 18 + o] = oacc[r] + bo;
        }
    }
    __syncthreads();   // As reads done (phase 2), offs visible

    // ---- Phase 3: bilinear sampling -> As ----
    float hm1 = (float)(hP - 1), wm1 = (float)(wP - 1);
#pragma unroll
    for (int tap = 0; tap < 9; ++tap) {
        float dy = offs[pr * 18 + 2 * tap];
        float dx = offs[pr * 18 + 2 * tap + 1];
        float py = dy + (float)(tap / 3) + hm1;
        float px = dx + (float)(tap % 3) + wm1;
        float y0f = floorf(py), x0f = floorf(px);
        float wy1 = py - y0f, wx1 = px - x0f;
        float wy0 = 1.f - wy1, wx0 = 1.f - wx1;
        int iy0 = (int)y0f, ix0 = (int)x0f;
        int iy1 = iy0 + 1,  ix1 = ix0 + 1;
        bool vy0 = (iy0 >= 0) && (iy0 < H), vy1 = (iy1 >= 0) && (iy1 < H);
        bool vx0 = (ix0 >= 0) && (ix0 < W), vx1 = (ix1 >= 0) && (ix1 < W);
        float w00 = (vy0 && vx0) ? wy0 * wx0 : 0.f;
        float w01 = (vy0 && vx1) ? wy0 * wx1 : 0.f;
        float w10 = (vy1 && vx0) ? wy1 * wx0 : 0.f;
        float w11 = (vy1 && vx1) ? wy1 * wx1 : 0.f;
        int cy0 = min(max(iy0, 0), H - 1), cy1 = min(max(iy1, 0), H - 1);
        int cx0 = min(max(ix0, 0), W - 1), cx1 = min(max(ix1, 0), W - 1);
        const uint16_t* basep = xTb + e8 * 8;
        bf16x8 v00 = *reinterpret_cast<const bf16x8*>(basep + (cy0 * W + cx0) * 64);
        bf16x8 v01 = *reinterpret_cast<const bf16x8*>(basep + (cy0 * W + cx1) * 64);
        bf16x8 v10 = *reinterpret_cast<const bf16x8*>(basep + (cy1 * W + cx0) * 64);
        bf16x8 v11 = *reinterpret_cast<const bf16x8*>(basep + (cy1 * W + cx1) * 64);
        bf16x8 outv;
#pragma unroll
        for (int e = 0; e < 8; ++e) {
            float s = w00 * bf2f((uint16_t)v00[e]) + w01 * bf2f((uint16_t)v01[e])
                    + w10 * bf2f((uint16_t)v10[e]) + w11 * bf2f((uint16_t)v11[e]);
            outv[e] = (short)f2bf(s);
        }
        *reinterpret_cast<bf16x8*>(&As[((tap * 64 + pr) * 8 + slot) * 8]) = outv;
    }
    __syncthreads();

    // ---- Phase 4: deform GEMM (N=64; rows wq*16.., N-frags wj*2+{0,1}) ----
    f32x4 acc[2];
    acc[0] = (f32x4){0.f, 0.f, 0.f, 0.f};
    acc[1] = (f32x4){0.f, 0.f, 0.f, 0.f};
#pragma unroll
    for (int s = 0; s < 18; ++s) {
        int sg = s * 4 + lg;
        bf16x8 a = *reinterpret_cast<const bf16x8*>(
            &As[(((sg >> 3) * 64 + wq * 16 + l15) * 8 + ((sg & 7) ^ (l15 & 7))) * 8]);
#pragma unroll
        for (int jj = 0; jj < 2; ++jj) {
            int j = wj * 2 + jj;
            bf16x8 bb = *reinterpret_cast<const bf16x8*>(
                wdefPack + (sg * 64 + j * 16 + l15) * 8);
            acc[jj] = __builtin_amdgcn_mfma_f32_16x16x32_bf16(a, bb, acc[jj], 0, 0, 0);
        }
    }

    // epilogue: C/D layout col=lane&15 (cout), row=(lane>>4)*4+reg (pixel)
#pragma unroll
    for (int jj = 0; jj < 2; ++jj) {
        int cout = (wj * 2 + jj) * 16 + l15;
        float* yp = y + ((size_t)b * Cout + cout) * HW + rem0 + 16 * wq + lg * 4;
        *reinterpret_cast<f32x4*>(yp) = acc[jj];
    }

    // BN partials
    if (tid < 128) s_red[tid] = 0.f;
    __syncthreads();
#pragma unroll
    for (int jj = 0; jj < 2; ++jj) {
        int j = wj * 2 + jj;
        float s = acc[jj][0] + acc[jj][1] + acc[jj][2] + acc[jj][3];
        float q = acc[jj][0]*acc[jj][0] + acc[jj][1]*acc[jj][1] +
                  acc[jj][2]*acc[jj][2] + acc[jj][3]*acc[jj][3];
        s += __shfl_xor(s, 16); s += __shfl_xor(s, 32);
        q += __shfl_xor(q, 16); q += __shfl_xor(q, 32);
        if (lg == 0) {
            atomicAdd(&s_red[j * 16 + l15], s);
            atomicAdd(&s_red[64 + j * 16 + l15], q);
        }
    }
    __syncthreads();
    if (tid < 128) partial[(size_t)wgid * 128 + tid] = s_red[tid];
}

// ---------------------------------------------------------------------------
// Kernel 3a: stage-1 BN reduce: 72 blocks x 16 tiles -> partial2[72][128]
// ---------------------------------------------------------------------------
__global__ __launch_bounds__(256) void bn_reduce1(const float* __restrict__ partial,
                                                  float* __restrict__ partial2) {
    __shared__ float red[256];
    int ch = threadIdx.x & 127;
    int g  = threadIdx.x >> 7;
    float s = 0.f;
#pragma unroll
    for (int r = 0; r < 8; ++r)
        s += partial[(size_t)(blockIdx.x * 16 + g * 8 + r) * 128 + ch];
    red[threadIdx.x] = s;
    __syncthreads();
    if (g == 0)
        partial2[(size_t)blockIdx.x * 128 + ch] = red[ch] + red[128 + ch];
}

// ---------------------------------------------------------------------------
// Kernel 3b: stage-2 -> per-channel scale/shift
// ---------------------------------------------------------------------------
__global__ void bn_stats2(const float* __restrict__ partial2,
                          const float* __restrict__ gamma,
                          const float* __restrict__ beta,
                          float* __restrict__ stats) {
    __shared__ float red[256];
    int ch = threadIdx.x & 127;
    int g  = threadIdx.x >> 7;
    float s = 0.f;
    for (int i = 0; i < 36; ++i)
        s += partial2[(size_t)(g * 36 + i) * 128 + ch];
    red[threadIdx.x] = s;
    __syncthreads();
    if (threadIdx.x < 64) {
        int c = threadIdx.x;
        float sum = red[c] + red[128 + c];
        float sq  = red[64 + c] + red[192 + c];
        float mean = sum / (float)NPIX;
        float var  = sq / (float)NPIX - mean * mean;
        float v    = var + EPS;
        float inv  = rsqrtf(v);
        inv = inv * (1.5f - 0.5f * v * inv * inv);
        float sc = gamma[c] * inv;
        stats[c]      = sc;
        stats[64 + c] = beta[c] - mean * sc;
    }
}

// ---------------------------------------------------------------------------
// Kernel 4: in-place scale/shift/ReLU, float4
// ---------------------------------------------------------------------------
__global__ __launch_bounds__(256) void bn_apply(float* __restrict__ y,
                                                const float* __restrict__ stats) {
    int t = blockIdx.x * blockDim.x + threadIdx.x;
    int e = t * 4;
    int ch = (e / HW) % Cout;
    float sc = stats[ch];
    float sh = stats[64 + ch];
    float4 v = *reinterpret_cast<float4*>(y + e);
    v.x = fmaxf(v.x * sc + sh, 0.f);
    v.y = fmaxf(v.y * sc + sh, 0.f);
    v.z = fmaxf(v.z * sc + sh, 0.f);
    v.w = fmaxf(v.w * sc + sh, 0.f);
    *reinterpret_cast<float4*>(y + e) = v;
}

// ---------------------------------------------------------------------------
extern "C" void kernel_launch(void* const* d_in, const int* in_sizes, int n_in,
                              void* d_out, int out_size, void* d_ws, size_t ws_size,
                              hipStream_t stream) {
    const float* x     = (const float*)d_in[0];
    const float* w_off = (const float*)d_in[1];
    const float* b_off = (const float*)d_in[2];
    const float* w_def = (const float*)d_in[3];
    // d_in[4] = b_def: constant shift, cancels exactly in BatchNorm — omitted
    const float* gamma = (const float*)d_in[5];
    const float* beta  = (const float*)d_in[6];
    float* out = (float*)d_out;
    char*  ws  = (char*)d_ws;

    // ws layout (bytes)
    uint16_t* xT       = (uint16_t*)ws;                    // 9,437,184
    uint16_t* woffPack = (uint16_t*)(ws + 9437184);        //    36,864
    uint16_t* wdefPack = (uint16_t*)(ws + 9474048);        //    73,728
    float*    partial  = (float*)(ws + 9547776);           //   589,824
    float*    partial2 = (float*)(ws + 10137600);          //    36,864
    float*    stats    = (float*)(ws + 10174464);          //       512

    repack<<<64, 256, 0, stream>>>(w_off, w_def, woffPack, wdefPack);
    transpose_x<<<NPIX * 2 / 256, 256, 0, stream>>>(x, xT);
    fused_deform<<<NBLK, 512, 0, stream>>>(xT, woffPack, wdefPack, b_off,
                                           out, partial);
    bn_reduce1<<<72, 256, 0, stream>>>(partial, partial2);
    bn_stats2<<<1, 256, 0, stream>>>(partial2, gamma, beta, stats);
    bn_apply<<<(NPIX * Cout / 4) / 256, 256, 0, stream>>>(out, stats);
}

// Round 6
// 69.263 us; speedup vs baseline: 10.6563x; 1.0257x over previous
//
#include <hip/hip_runtime.h>
#include <hip/hip_bf16.h>
#include <stdint.h>

static constexpr int NBATCH = 8;
static constexpr int Cin  = 64;
static constexpr int Cout = 64;
static constexpr int H = 96, W = 96;
static constexpr int HW   = H * W;          // 9216
static constexpr int NPIX = NBATCH * HW;    // 73728
static constexpr int NBLK = NPIX / 64;      // 1152
static constexpr int BLK_PER_BATCH = HW / 64; // 144
static constexpr float EPS = 1e-5f;

typedef short  bf16x8 __attribute__((ext_vector_type(8)));
typedef float  f32x4  __attribute__((ext_vector_type(4)));

__device__ inline uint16_t f2bf(float f) {
    __hip_bfloat16 h = __float2bfloat16(f);
    return *reinterpret_cast<uint16_t*>(&h);
}
__device__ inline float bf2f(uint16_t u) {
    union { uint32_t i; float f; } z;
    z.i = ((uint32_t)u) << 16;
    return z.f;
}

// ---------------------------------------------------------------------------
// Kernel 0: pack weights into MFMA B-fragment order, bf16.
//   layout [sg:72][n][e:8], value = w[n][c][tap], k = sg*8+e, tap=k>>6, c=k&63
// ---------------------------------------------------------------------------
__global__ void repack(const float* __restrict__ w_off,
                       const float* __restrict__ w_def,
                       uint16_t* __restrict__ woffPack,
                       uint16_t* __restrict__ wdefPack) {
    int t0 = blockIdx.x * blockDim.x + threadIdx.x;
    int stride = gridDim.x * blockDim.x;
    for (int i = t0; i < 72 * 32 * 8; i += stride) {
        int e = i & 7;
        int n = (i >> 3) & 31;
        int sg = i >> 8;
        int k = sg * 8 + e;
        int tap = k >> 6, c = k & 63;
        woffPack[i] = (n < 18) ? f2bf(w_off[(n * Cin + c) * 9 + tap]) : (uint16_t)0;
    }
    for (int i = t0; i < 72 * 64 * 8; i += stride) {
        int e = i & 7;
        int n = (i >> 3) & 63;
        int sg = i >> 9;
        int k = sg * 8 + e;
        int tap = k >> 6, c = k & 63;
        wdefPack[i] = f2bf(w_def[(n * Cin + c) * 9 + tap]);
    }
}

// ---------------------------------------------------------------------------
// Kernel 1: transpose x (NCHW f32) -> xT (N,HW,C) bf16. 2 threads/pixel.
// ---------------------------------------------------------------------------
__global__ __launch_bounds__(256) void transpose_x(const float* __restrict__ x,
                                                   uint16_t* __restrict__ xT) {
    int t = blockIdx.x * 256 + threadIdx.x;      // exact grid: NPIX*2 threads
    int pix  = t >> 1;
    int half = t & 1;
    int b = pix / HW, rem = pix % HW;
    const float* xb = x + (size_t)(b * Cin) * HW + rem + (size_t)(half * 32) * HW;
    uint16_t* o = xT + (size_t)pix * 64 + half * 32;
#pragma unroll
    for (int cg = 0; cg < 4; ++cg) {
        bf16x8 v;
#pragma unroll
        for (int e = 0; e < 8; ++e) v[e] = (short)f2bf(xb[(cg * 8 + e) * HW]);
        *reinterpret_cast<bf16x8*>(o + cg * 8) = v;
    }
}

// ---------------------------------------------------------------------------
// Kernel 2: fused deformable block, 512 threads / 64-pixel tile.
// LDS As: [tap:9][pix:64][slot:8][8 bf16], slot = chunk ^ (pix&7).
// GEMM phases use B-fragment reuse: each wave loads a B fragment ONCE and
// applies it to 4 A fragments (M=64), with K split across waves; partial
// accumulators reduced through LDS buffers ALIASED over As (barrier-guarded).
//  P1: plain 3x3 im2col -> As
//  P2: offset GEMM, wave=(wj:2, kq:4) K-quarters -> osum -> offs[64][18]
//  P3: bilinear sampling -> As (overwrite)
//  P4: deform GEMM, wave=(nf:4, kh:2) K-halves -> red -> y (+ BN partials)
// ---------------------------------------------------------------------------
__global__ __launch_bounds__(512, 4) void fused_deform(
        const uint16_t* __restrict__ xT,
        const uint16_t* __restrict__ woffPack,
        const uint16_t* __restrict__ wdefPack,
        const float* __restrict__ b_off,
        float* __restrict__ y,
        float* __restrict__ partial) {
    __shared__ __attribute__((aligned(16))) char smem[73728];
    __shared__ float offs[64 * 18];       //  4608 B
    __shared__ float s_red[128];          //   512 B
    short* As   = (short*)smem;           // bf16 im2col tile
    float* osum = (float*)smem;           // [4][64][34] (alias, after P2 reads)
    float* red  = (float*)smem;           // [2][64][66] (alias, after P4 reads)

    int tid  = threadIdx.x;
    int lane = tid & 63;
    int wv   = tid >> 6;                  // 0..7
    int l15  = lane & 15;
    int lg   = lane >> 4;

    // XCD-aware swizzle: batch b -> XCD b
    int wgid  = (blockIdx.x & 7) * BLK_PER_BATCH + (blockIdx.x >> 3);
    int gpix0 = wgid * 64;
    int b     = gpix0 / HW;
    int rem0  = gpix0 % HW;
    const uint16_t* xTb = xT + (size_t)b * HW * 64;

    // pixel-major mapping for gather phases
    int pr   = (wv << 3) + (lane >> 3);   // local pixel 0..63
    int e8   = lane & 7;                  // channel chunk (8 ch = 16B)
    int slot = e8 ^ (pr & 7);             // LDS bank swizzle
    int remP = rem0 + pr;
    int hP   = remP / W, wP = remP % W;

    // ---- Phase 1: plain im2col ----
#pragma unroll
    for (int tap = 0; tap < 9; ++tap) {
        int yy = hP + tap / 3 - 1;
        int xx = wP + tap % 3 - 1;
        bf16x8 v = (bf16x8){0, 0, 0, 0, 0, 0, 0, 0};
        if (yy >= 0 && yy < H && xx >= 0 && xx < W)
            v = *reinterpret_cast<const bf16x8*>(xTb + (yy * W + xx) * 64 + e8 * 8);
        *reinterpret_cast<bf16x8*>(&As[((tap * 64 + pr) * 8 + slot) * 8]) = v;
    }
    __syncthreads();

    // ---- Phase 2: offset GEMM. wave = (wj = wv&1 N-frag, kq = wv>>1 K-qtr) ----
    {
        int wj = wv & 1;
        int kq = wv >> 1;
        int sbeg = (kq < 2) ? kq * 5 : 2 + kq * 4;     // 0,5,10,14
        int send = (kq < 2) ? sbeg + 5 : sbeg + 4;
        f32x4 oacc[4];
#pragma unroll
        for (int m = 0; m < 4; ++m) oacc[m] = (f32x4){0.f, 0.f, 0.f, 0.f};
        for (int s = sbeg; s < send; ++s) {
            int sg = s * 4 + lg;
            bf16x8 bb = *reinterpret_cast<const bf16x8*>(
                woffPack + (sg * 32 + wj * 16 + l15) * 8);
#pragma unroll
            for (int m = 0; m < 4; ++m) {
                bf16x8 a = *reinterpret_cast<const bf16x8*>(
                    &As[(((sg >> 3) * 64 + m * 16 + l15) * 8 + ((sg & 7) ^ (l15 & 7))) * 8]);
                oacc[m] = __builtin_amdgcn_mfma_f32_16x16x32_bf16(a, bb, oacc[m], 0, 0, 0);
            }
        }
        __syncthreads();     // all As reads done -> safe to alias osum over As
#pragma unroll
        for (int m = 0; m < 4; ++m)
#pragma unroll
            for (int r = 0; r < 4; ++r)
                osum[(kq * 64 + m * 16 + lg * 4 + r) * 34 + wj * 16 + l15] = oacc[m][r];
        __syncthreads();
        for (int i = tid; i < 64 * 18; i += 512) {
            int rr = i / 18, o = i - rr * 18;
            offs[i] = osum[rr * 34 + o] + osum[(64 + rr) * 34 + o]
                    + osum[(128 + rr) * 34 + o] + osum[(192 + rr) * 34 + o] + b_off[o];
        }
        if (tid < 128) s_red[tid] = 0.f;
        __syncthreads();
    }

    // ---- Phase 3: bilinear sampling -> As (overwrites osum alias too) ----
    float hm1 = (float)(hP - 1), wm1 = (float)(wP - 1);
#pragma unroll
    for (int tap = 0; tap < 9; ++tap) {
        float dy = offs[pr * 18 + 2 * tap];
        float dx = offs[pr * 18 + 2 * tap + 1];
        float py = dy + (float)(tap / 3) + hm1;
        float px = dx + (float)(tap % 3) + wm1;
        float y0f = floorf(py), x0f = floorf(px);
        float wy1 = py - y0f, wx1 = px - x0f;
        float wy0 = 1.f - wy1, wx0 = 1.f - wx1;
        int iy0 = (int)y0f, ix0 = (int)x0f;
        int iy1 = iy0 + 1,  ix1 = ix0 + 1;
        bool vy0 = (iy0 >= 0) && (iy0 < H), vy1 = (iy1 >= 0) && (iy1 < H);
        bool vx0 = (ix0 >= 0) && (ix0 < W), vx1 = (ix1 >= 0) && (ix1 < W);
        float w00 = (vy0 && vx0) ? wy0 * wx0 : 0.f;
        float w01 = (vy0 && vx1) ? wy0 * wx1 : 0.f;
        float w10 = (vy1 && vx0) ? wy1 * wx0 : 0.f;
        float w11 = (vy1 && vx1) ? wy1 * wx1 : 0.f;
        int cy0 = min(max(iy0, 0), H - 1), cy1 = min(max(iy1, 0), H - 1);
        int cx0 = min(max(ix0, 0), W - 1), cx1 = min(max(ix1, 0), W - 1);
        const uint16_t* basep = xTb + e8 * 8;
        bf16x8 v00 = *reinterpret_cast<const bf16x8*>(basep + (cy0 * W + cx0) * 64);
        bf16x8 v01 = *reinterpret_cast<const bf16x8*>(basep + (cy0 * W + cx1) * 64);
        bf16x8 v10 = *reinterpret_cast<const bf16x8*>(basep + (cy1 * W + cx0) * 64);
        bf16x8 v11 = *reinterpret_cast<const bf16x8*>(basep + (cy1 * W + cx1) * 64);
        bf16x8 outv;
#pragma unroll
        for (int e = 0; e < 8; ++e) {
            float s = w00 * bf2f((uint16_t)v00[e]) + w01 * bf2f((uint16_t)v01[e])
                    + w10 * bf2f((uint16_t)v10[e]) + w11 * bf2f((uint16_t)v11[e]);
            outv[e] = (short)f2bf(s);
        }
        *reinterpret_cast<bf16x8*>(&As[((tap * 64 + pr) * 8 + slot) * 8]) = outv;
    }
    __syncthreads();

    // ---- Phase 4: deform GEMM. wave = (nf = wv&3 N-frag, kh = wv>>2 K-half) ----
    {
        int nf = wv & 3;
        int kh = wv >> 2;
        f32x4 acc[4];
#pragma unroll
        for (int m = 0; m < 4; ++m) acc[m] = (f32x4){0.f, 0.f, 0.f, 0.f};
#pragma unroll
        for (int s = 0; s < 9; ++s) {
            int sg = (kh * 9 + s) * 4 + lg;
            bf16x8 bb = *reinterpret_cast<const bf16x8*>(
                wdefPack + (sg * 64 + nf * 16 + l15) * 8);
#pragma unroll
            for (int m = 0; m < 4; ++m) {
                bf16x8 a = *reinterpret_cast<const bf16x8*>(
                    &As[(((sg >> 3) * 64 + m * 16 + l15) * 8 + ((sg & 7) ^ (l15 & 7))) * 8]);
                acc[m] = __builtin_amdgcn_mfma_f32_16x16x32_bf16(a, bb, acc[m], 0, 0, 0);
            }
        }
        __syncthreads();     // all As reads done -> safe to alias red over As
#pragma unroll
        for (int m = 0; m < 4; ++m)
#pragma unroll
            for (int r = 0; r < 4; ++r)
                red[(kh * 64 + m * 16 + lg * 4 + r) * 66 + nf * 16 + l15] = acc[m][r];
        __syncthreads();

        // final: thread (c = lane, rg = wv) -> rows rg*8..rg*8+7, cout c
        int c  = lane;
        int rg = wv;
        f32x4 v0, v1;
        float s = 0.f, q = 0.f;
#pragma unroll
        for (int k2 = 0; k2 < 8; ++k2) {
            int r = rg * 8 + k2;
            float v = red[r * 66 + c] + red[(64 + r) * 66 + c];
            if (k2 < 4) v0[k2] = v; else v1[k2 - 4] = v;
            s += v; q += v * v;
        }
        float* yp = y + ((size_t)b * Cout + c) * HW + rem0 + rg * 8;
        *reinterpret_cast<f32x4*>(yp)     = v0;
        *reinterpret_cast<f32x4*>(yp + 4) = v1;
        atomicAdd(&s_red[c], s);
        atomicAdd(&s_red[64 + c], q);
    }
    __syncthreads();
    if (tid < 128) partial[(size_t)wgid * 128 + tid] = s_red[tid];
}

// ---------------------------------------------------------------------------
// Kernel 3a: stage-1 BN reduce: 72 blocks x 16 tiles -> partial2[72][128]
// ---------------------------------------------------------------------------
__global__ __launch_bounds__(256) void bn_reduce1(const float* __restrict__ partial,
                                                  float* __restrict__ partial2) {
    __shared__ float red[256];
    int ch = threadIdx.x & 127;
    int g  = threadIdx.x >> 7;
    float s = 0.f;
#pragma unroll
    for (int r = 0; r < 8; ++r)
        s += partial[(size_t)(blockIdx.x * 16 + g * 8 + r) * 128 + ch];
    red[threadIdx.x] = s;
    __syncthreads();
    if (g == 0)
        partial2[(size_t)blockIdx.x * 128 + ch] = red[ch] + red[128 + ch];
}

// ---------------------------------------------------------------------------
// Kernel 3b: stage-2 -> per-channel scale/shift
// ---------------------------------------------------------------------------
__global__ void bn_stats2(const float* __restrict__ partial2,
                          const float* __restrict__ gamma,
                          const float* __restrict__ beta,
                          float* __restrict__ stats) {
    __shared__ float red[256];
    int ch = threadIdx.x & 127;
    int g  = threadIdx.x >> 7;
    float s = 0.f;
    for (int i = 0; i < 36; ++i)
        s += partial2[(size_t)(g * 36 + i) * 128 + ch];
    red[threadIdx.x] = s;
    __syncthreads();
    if (threadIdx.x < 64) {
        int c = threadIdx.x;
        float sum = red[c] + red[128 + c];
        float sq  = red[64 + c] + red[192 + c];
        float mean = sum / (float)NPIX;
        float var  = sq / (float)NPIX - mean * mean;
        float v    = var + EPS;
        float inv  = rsqrtf(v);
        inv = inv * (1.5f - 0.5f * v * inv * inv);
        float sc = gamma[c] * inv;
        stats[c]      = sc;
        stats[64 + c] = beta[c] - mean * sc;
    }
}

// ---------------------------------------------------------------------------
// Kernel 4: in-place scale/shift/ReLU, float4
// ---------------------------------------------------------------------------
__global__ __launch_bounds__(256) void bn_apply(float* __restrict__ y,
                                                const float* __restrict__ stats) {
    int t = blockIdx.x * blockDim.x + threadIdx.x;
    int e = t * 4;
    int ch = (e / HW) % Cout;
    float sc = stats[ch];
    float sh = stats[64 + ch];
    float4 v = *reinterpret_cast<float4*>(y + e);
    v.x = fmaxf(v.x * sc + sh, 0.f);
    v.y = fmaxf(v.y * sc + sh, 0.f);
    v.z = fmaxf(v.z * sc + sh, 0.f);
    v.w = fmaxf(v.w * sc + sh, 0.f);
    *reinterpret_cast<float4*>(y + e) = v;
}

// ---------------------------------------------------------------------------
extern "C" void kernel_launch(void* const* d_in, const int* in_sizes, int n_in,
                              void* d_out, int out_size, void* d_ws, size_t ws_size,
                              hipStream_t stream) {
    const float* x     = (const float*)d_in[0];
    const float* w_off = (const float*)d_in[1];
    const float* b_off = (const float*)d_in[2];
    const float* w_def = (const float*)d_in[3];
    // d_in[4] = b_def: constant shift, cancels exactly in BatchNorm — omitted
    const float* gamma = (const float*)d_in[5];
    const float* beta  = (const float*)d_in[6];
    float* out = (float*)d_out;
    char*  ws  = (char*)d_ws;

    // ws layout (bytes)
    uint16_t* xT       = (uint16_t*)ws;                    // 9,437,184
    uint16_t* woffPack = (uint16_t*)(ws + 9437184);        //    36,864
    uint16_t* wdefPack = (uint16_t*)(ws + 9474048);        //    73,728
    float*    partial  = (float*)(ws + 9547776);           //   589,824
    float*    partial2 = (float*)(ws + 10137600);          //    36,864
    float*    stats    = (float*)(ws + 10174464);          //       512

    repack<<<64, 256, 0, stream>>>(w_off, w_def, woffPack, wdefPack);
    transpose_x<<<NPIX * 2 / 256, 256, 0, stream>>>(x, xT);
    fused_deform<<<NBLK, 512, 0, stream>>>(xT, woffPack, wdefPack, b_off,
                                           out, partial);
    bn_reduce1<<<72, 256, 0, stream>>>(partial, partial2);
    bn_stats2<<<1, 256, 0, stream>>>(partial2, gamma, beta, stats);
    bn_apply<<<(NPIX * Cout / 4) / 256, 256, 0, stream>>>(out, stats);
}